// Round 8
// baseline (1272.017 us; speedup 1.0000x reference)
//
#include <hip/hip_runtime.h>
#include <hip/hip_bf16.h>

// GptOss grouped experts, round 8: delivery-bound model.
// 1-barrier K-loop: all tile-t ds_reads drain (lgkm0) before the single
// barrier; stage(cur,t+2) after it is race-free; vmcnt(0) drains loads
// issued one full iteration earlier (non-stalling). gemm1: BM=256xBN=384
// (FN=6), LDS 160 KB exactly, grid 960 (3.75 rounds). gemm2: BN=320 (FN=5).
// cvt_w2 folded into gemm1 epilogue (runs in gemm1's HBM shadow).
// T1 XCD swizzle, T2 XOR swizzle (inverse-swizzled source), T5 setprio.

#define TT   16384
#define DIM_ 2880
#define HID_ 2880
#define NE   8
#define TPE  2048
#define KDIM 2880
#define NT   45     // KDIM / 64

typedef __attribute__((ext_vector_type(8))) short short8;
typedef __attribute__((ext_vector_type(4))) float f32x4;

__device__ __forceinline__ unsigned short f2bf(float f) {
  unsigned u = __builtin_bit_cast(unsigned, f);
  u += 0x7fffu + ((u >> 16) & 1u);   // round-to-nearest-even
  return (unsigned short)(u >> 16);
}

__global__ void __launch_bounds__(256) cvt_f32_bf16(const float* __restrict__ src,
                                                    unsigned short* __restrict__ dst,
                                                    long n) {
  long i = ((long)blockIdx.x * 256 + threadIdx.x) * 8;
  if (i >= n) return;
  float4 a = *(const float4*)(src + i);
  float4 b = *(const float4*)(src + i + 4);
  union { unsigned short u[8]; short8 v; } r;
  r.u[0] = f2bf(a.x); r.u[1] = f2bf(a.y); r.u[2] = f2bf(a.z); r.u[3] = f2bf(a.w);
  r.u[4] = f2bf(b.x); r.u[5] = f2bf(b.y); r.u[6] = f2bf(b.z); r.u[7] = f2bf(b.w);
  *(short8*)(dst + i) = r.v;
}

#define GLDS(gsrc, ldst) \
  __builtin_amdgcn_global_load_lds( \
      (const __attribute__((address_space(1))) unsigned int*)(gsrc), \
      (__attribute__((address_space(3))) unsigned int*)(ldst), 16, 0, 0)

// C = A(MxK) * B(NxK)^T, bf16 in, fp32 accum. BM=256, BN=64*FN, BK=64.
// 512 threads = 8 waves (2M x 4N); per-wave 128 x (FN*16).
// LDS: dbuf x (A 32KB + B FN*8KB).
template<int FN, bool FUSE_SWIGLU>
__global__ void __launch_bounds__(512, 2) gemmk(const unsigned short* __restrict__ A,
                                                const unsigned short* __restrict__ B,
                                                const float* __restrict__ bias,
                                                void* __restrict__ Cout,
                                                int M, int N,
                                                const float* __restrict__ cvt_src,
                                                unsigned short* __restrict__ cvt_dst,
                                                long cvt_n) {
  constexpr int BN = 64 * FN;
  __shared__ unsigned short As[2][256 * 64];
  __shared__ unsigned short Bs[2][BN * 64];

  const int tid  = threadIdx.x;
  const int lane = tid & 63;
  const int wid  = tid >> 6;
  const int wr   = wid >> 2;        // 0..1
  const int wc   = wid & 3;         // 0..3
  const int e    = blockIdx.z;

  // T1: per-expert bijective XCD swizzle (per_e % 8 == 0 in both GEMMs).
  const int ntn   = N / BN;
  const int ntm   = M / 256;
  const int per_e = ntn * ntm;
  const int bid   = blockIdx.x;
  const int swz   = (bid & 7) * (per_e >> 3) + (bid >> 3);
  const int m0    = (swz / ntn) * 256;
  const int n0    = (swz % ntn) * BN;

  // staging: 8 lanes/row, 16B/lane; T2 inverse-swizzle on source column
  const int srow = tid >> 3;                         // 0..63
  const int scol = ((tid & 7) ^ (srow & 7)) << 3;    // elements
  const unsigned short* Aexp = A + ((size_t)e * M + m0 + srow) * KDIM + scol;
  const unsigned short* Bexp = B + ((size_t)e * N + n0 + srow) * KDIM + scol;

  auto stage = [&](int buf, int kt) {
    const unsigned short* asrc = Aexp + (size_t)kt * 64;
#pragma unroll
    for (int j = 0; j < 4; ++j)
      GLDS(asrc + (size_t)(j * 64) * KDIM, &As[buf][j * 4096 + tid * 8]);
    const unsigned short* bsrc = Bexp + (size_t)kt * 64;
#pragma unroll
    for (int j = 0; j < FN; ++j)
      GLDS(bsrc + (size_t)(j * 64) * KDIM, &Bs[buf][j * 4096 + tid * 8]);
  };

  // fragment-read addressing (swizzled), byte offsets; row stride 128 B
  const int arow = (wr * 128 + (lane & 15)) * 128;
  const int brow = (wc * (FN * 16) + (lane & 15)) * 128;
  const int swzb = (lane & 7) << 4;
  const int kb   = ((lane >> 4) & 3) * 16;
  const int c0 = kb ^ swzb;          // kk=0
  const int c1 = (64 + kb) ^ swzb;   // kk=1

  f32x4 acc[8][FN] = {};

  // prologue: tiles 0,1 staged (4+FN loads each); wait tile 0.
  stage(0, 0);
  stage(1, 1);
  if constexpr (FN == 6) asm volatile("s_waitcnt vmcnt(10)" ::: "memory");
  else                   asm volatile("s_waitcnt vmcnt(9)"  ::: "memory");
  __builtin_amdgcn_s_barrier();

  for (int t = 0; t < NT; ++t) {
    const int cur = t & 1;
    const char* aB = (const char*)(&As[cur][0]) + arow;
    const char* bB = (const char*)(&Bs[cur][0]) + brow;

    short8 a[8], b[FN];

    // kk=0: read frags, MFMA (compiler interleaves with counted lgkmcnt)
#pragma unroll
    for (int fm = 0; fm < 8; ++fm) a[fm] = *(const short8*)(aB + fm * 2048 + c0);
#pragma unroll
    for (int fn = 0; fn < FN; ++fn) b[fn] = *(const short8*)(bB + fn * 2048 + c0);
    __builtin_amdgcn_s_setprio(1);
#pragma unroll
    for (int fn = 0; fn < FN; ++fn)
#pragma unroll
      for (int fm = 0; fm < 8; ++fm)
        acc[fm][fn] = __builtin_amdgcn_mfma_f32_16x16x32_bf16(a[fm], b[fn], acc[fm][fn], 0, 0, 0);
    __builtin_amdgcn_s_setprio(0);

    // kk=1
#pragma unroll
    for (int fm = 0; fm < 8; ++fm) a[fm] = *(const short8*)(aB + fm * 2048 + c1);
#pragma unroll
    for (int fn = 0; fn < FN; ++fn) b[fn] = *(const short8*)(bB + fn * 2048 + c1);
    __builtin_amdgcn_s_setprio(1);
#pragma unroll
    for (int fn = 0; fn < FN; ++fn)
#pragma unroll
      for (int fm = 0; fm < 8; ++fm)
        acc[fm][fn] = __builtin_amdgcn_mfma_f32_16x16x32_bf16(a[fm], b[fn], acc[fm][fn], 0, 0, 0);
    __builtin_amdgcn_s_setprio(0);

    // single sync point: own reads done (lgkm0); tile t+1's staging (issued
    // one iteration ago) done (vmcnt0, non-stalling); barrier -> true for all
    // waves; then overwrite buf[cur] with tile t+2.
    asm volatile("s_waitcnt lgkmcnt(0)" ::: "memory");
    asm volatile("s_waitcnt vmcnt(0)" ::: "memory");
    __builtin_amdgcn_s_barrier();
    if (t + 2 < NT) stage(cur, t + 2);
  }

  // ---- epilogue
  const float* be = bias + (size_t)e * N;
  if constexpr (FUSE_SWIGLU) {
    unsigned short* ha = (unsigned short*)Cout + (size_t)e * M * (N >> 1);
#pragma unroll
    for (int fm = 0; fm < 8; ++fm)
#pragma unroll
      for (int fn = 0; fn < FN; ++fn) {
        const int col = n0 + wc * (FN * 16) + fn * 16 + (lane & 15);
        const float bc = be[col];
#pragma unroll
        for (int j = 0; j < 4; ++j) {
          const int row = m0 + wr * 128 + fm * 16 + (lane >> 4) * 4 + j;
          float v = acc[fm][fn][j] + bc;
          float p = __shfl_xor(v, 1);   // partner column (all lanes execute)
          if (!(lane & 1)) {
            float g  = fminf(v, 7.0f);
            float l2 = fminf(fmaxf(p, -7.0f), 7.0f);
            float act = g / (1.0f + __expf(-1.702f * g)) * (l2 + 1.0f);
            ha[(size_t)row * (N >> 1) + (col >> 1)] = f2bf(act);
          }
        }
      }
    // folded cvt (w2 fp32->bf16) in gemm1's HBM shadow
    const long stride = (long)gridDim.x * gridDim.z * 512 * 8;
    long i = ((long)(blockIdx.z * gridDim.x + blockIdx.x) * 512 + tid) * 8;
    for (; i < cvt_n; i += stride) {
      float4 va = *(const float4*)(cvt_src + i);
      float4 vb = *(const float4*)(cvt_src + i + 4);
      union { unsigned short u[8]; short8 v; } r;
      r.u[0] = f2bf(va.x); r.u[1] = f2bf(va.y); r.u[2] = f2bf(va.z); r.u[3] = f2bf(va.w);
      r.u[4] = f2bf(vb.x); r.u[5] = f2bf(vb.y); r.u[6] = f2bf(vb.z); r.u[7] = f2bf(vb.w);
      *(short8*)(cvt_dst + i) = r.v;
    }
  } else {
    float* out = (float*)Cout + (size_t)e * M * N;
#pragma unroll
    for (int fm = 0; fm < 8; ++fm)
#pragma unroll
      for (int fn = 0; fn < FN; ++fn) {
        const int col = n0 + wc * (FN * 16) + fn * 16 + (lane & 15);
        const float bc = be[col];
#pragma unroll
        for (int j = 0; j < 4; ++j) {
          const int row = m0 + wr * 128 + fm * 16 + (lane >> 4) * 4 + j;
          out[(size_t)row * N + col] = acc[fm][fn][j] + bc;
        }
      }
  }
}

extern "C" void kernel_launch(void* const* d_in, const int* in_sizes, int n_in,
                              void* d_out, int out_size, void* d_ws, size_t ws_size,
                              hipStream_t stream) {
  const float* x  = (const float*)d_in[0];
  // d_in[1] = num_tokens_per_expert: fixed T/E split (reference ignores it)
  const float* w1 = (const float*)d_in[2];
  const float* b1 = (const float*)d_in[3];
  const float* w2 = (const float*)d_in[4];
  const float* b2 = (const float*)d_in[5];

  unsigned short* xb  = (unsigned short*)d_ws;
  unsigned short* w1b = xb  + (size_t)TT * DIM_;
  unsigned short* w2b = w1b + (size_t)NE * 2 * HID_ * DIM_;
  unsigned short* ha  = w2b + (size_t)NE * DIM_ * HID_;

  const long nx = (long)TT * DIM_;             // 47,185,920
  const long n1 = (long)NE * 2 * HID_ * DIM_;  // 132,710,400
  const long n2 = (long)NE * DIM_ * HID_;      // 66,355,200
  cvt_f32_bf16<<<(int)(nx / 2048), 256, 0, stream>>>(x,  xb,  nx);
  cvt_f32_bf16<<<(int)(n1 / 2048), 256, 0, stream>>>(w1, w1b, n1);

  // GEMM1 + bias + swiglu -> ha (bf16 [E][2048][2880]); also converts w2 in
  // its epilogue (compute-bound shadow).
  dim3 g1(5760 / 384 * (TPE / 256), 1, NE);    // 15*8 = 120 per expert
  gemmk<6, true><<<g1, 512, 0, stream>>>(xb, w1b, b1, ha, TPE, 5760, w2, w2b, n2);

  // GEMM2 + bias -> out (fp32 [T][2880])
  dim3 g2(DIM_ / 320 * (TPE / 256), 1, NE);    // 9*8 = 72 per expert
  gemmk<5, false><<<g2, 512, 0, stream>>>(ha, w2b, b2, (float*)d_out, TPE, DIM_,
                                          nullptr, nullptr, 0);
}